// Round 4
// baseline (276.763 us; speedup 1.0000x reference)
//
#include <hip/hip_runtime.h>
#include <hip/hip_fp16.h>

#define N_SEQ 8192
#define E_DIM 768
#define D_OUT 64
#define PADK 68                       // 64 + 4 pad -> 136B rows: proven 0-conflict layout
#define SCALE_LOG2 0.18033688011112042f   // 1/(8*ln2): fold softmax scale + log2e into Q

typedef __attribute__((ext_vector_type(8)))  short s16x8;
typedef __attribute__((ext_vector_type(4)))  float f32x4;
typedef __attribute__((ext_vector_type(16))) float f32x16;

static __device__ __forceinline__ unsigned short f2bf(float f) {
    union { float f; unsigned int u; } v; v.f = f;
    unsigned int r = v.u + 0x7FFFu + ((v.u >> 16) & 1u);   // RNE
    return (unsigned short)(r >> 16);
}
static __device__ __forceinline__ float bf2f(unsigned short h) {
    union { float f; unsigned int u; } v; v.u = ((unsigned int)h) << 16; return v.f;
}
static __device__ __forceinline__ s16x8 gfrag(const unsigned short* p) {
    union { uint4 u; s16x8 s; } r; r.u = *(const uint4*)p; return r.s;
}
static __device__ __forceinline__ s16x8 ldsfrag(const unsigned short* p) {
    union { uint2 u[2]; s16x8 s; } r;
    r.u[0] = *(const uint2*)(p);
    r.u[1] = *(const uint2*)(p + 4);
    return r.s;
}
// pack two f32 -> bf16x2 by truncation via v_perm (bias cancels: same P feeds O and l)
static __device__ __forceinline__ unsigned int packbf(float a, float b) {
    return __builtin_amdgcn_perm(__float_as_uint(b), __float_as_uint(a), 0x07060302u);
}
// 32B store as 4x b64 (PADK rows are 8B-aligned, not 16B)
static __device__ __forceinline__ void st32(unsigned short* d, uint4 a, uint4 b) {
    uint2* p = (uint2*)d;
    p[0] = make_uint2(a.x, a.y); p[1] = make_uint2(a.z, a.w);
    p[2] = make_uint2(b.x, b.y); p[3] = make_uint2(b.z, b.w);
}

// ---------------- Kernel 1: fused prep (X -> bf16 hi/lo; W -> Wt hi/lo) ------
// blocks [0, 6144): X float4 path.  blocks [6144, 6720): W transpose path.
__global__ __launch_bounds__(256) void prep(const float* __restrict__ X,
                                            const float* __restrict__ WQ,
                                            const float* __restrict__ WK,
                                            const float* __restrict__ WV,
                                            unsigned short* __restrict__ Xhi,
                                            unsigned short* __restrict__ Xlo,
                                            unsigned short* __restrict__ Wthi,
                                            unsigned short* __restrict__ Wtlo) {
    int bx = blockIdx.x;
    if (bx < 6144) {
        int idx = bx * 256 + threadIdx.x;          // over float4: 8192*768/4
        float4 v = ((const float4*)X)[idx];
        ushort4 hi, lo;
        hi.x = f2bf(v.x); lo.x = f2bf(v.x - bf2f(hi.x));
        hi.y = f2bf(v.y); lo.y = f2bf(v.y - bf2f(hi.y));
        hi.z = f2bf(v.z); lo.z = f2bf(v.z - bf2f(hi.z));
        hi.w = f2bf(v.w); lo.w = f2bf(v.w - bf2f(hi.w));
        ((ushort4*)Xhi)[idx] = hi;
        ((ushort4*)Xlo)[idx] = lo;
    } else {
        int idx = (bx - 6144) * 256 + threadIdx.x;   // 192*768 total
        if (idx >= 192 * E_DIM) return;
        int n = idx / E_DIM;
        int k = idx - n * E_DIM;
        float v;
        if (n < 64)       v = WQ[k * 64 + n];
        else if (n < 128) v = WK[k * 64 + (n - 64)];
        else              v = WV[k * 64 + (n - 128)];
        unsigned short hb = f2bf(v);
        Wthi[idx] = hb;
        Wtlo[idx] = f2bf(v - bf2f(hb));
    }
}

// ---------------- Kernel 2: QKV projection (fused Q/K/V per wave) ------------
// One wave per block, 2048 blocks -> 8 blocks/CU for even distribution.
__global__ __launch_bounds__(64, 4) void proj_qkv(const unsigned short* __restrict__ Xhi,
                                                  const unsigned short* __restrict__ Xlo,
                                                  const unsigned short* __restrict__ Wthi,
                                                  const unsigned short* __restrict__ Wtlo,
                                                  unsigned short* __restrict__ Qhi,
                                                  unsigned short* __restrict__ Qlo,
                                                  unsigned short* __restrict__ Khi,
                                                  unsigned short* __restrict__ Klo,
                                                  unsigned short* __restrict__ Vt) {
    int lane = threadIdx.x;                  // 0..63
    int id   = blockIdx.x;                   // 0..2047
    int mt   = id >> 2;
    int c    = id & 3;                       // 16-col block within D=64
    int m0 = mt * 16, n0 = c * 16;
    int lr = lane & 15, lk = lane >> 4;      // row-in-tile, k-quad

    f32x4 aQ, aK, aV;
    #pragma unroll
    for (int i = 0; i < 4; ++i) { aQ[i] = 0.f; aK[i] = 0.f; aV[i] = 0.f; }

    const unsigned short* xh  = Xhi  + (size_t)(m0 + lr) * E_DIM + lk * 8;
    const unsigned short* xl  = Xlo  + (size_t)(m0 + lr) * E_DIM + lk * 8;
    const unsigned short* wqh = Wthi + (size_t)(n0 + lr) * E_DIM + lk * 8;
    const unsigned short* wql = Wtlo + (size_t)(n0 + lr) * E_DIM + lk * 8;
    const unsigned short* wkh = Wthi + (size_t)(64 + n0 + lr) * E_DIM + lk * 8;
    const unsigned short* wkl = Wtlo + (size_t)(64 + n0 + lr) * E_DIM + lk * 8;
    const unsigned short* wvh = Wthi + (size_t)(128 + n0 + lr) * E_DIM + lk * 8;

    #pragma unroll 2
    for (int ks = 0; ks < E_DIM / 32; ++ks) {
        int kb = ks * 32;
        s16x8 ah = gfrag(xh + kb);
        s16x8 al = gfrag(xl + kb);
        s16x8 bqh = gfrag(wqh + kb);
        s16x8 bql = gfrag(wql + kb);
        s16x8 bkh = gfrag(wkh + kb);
        s16x8 bkl = gfrag(wkl + kb);
        s16x8 bvh = gfrag(wvh + kb);
        aQ = __builtin_amdgcn_mfma_f32_16x16x32_bf16(ah, bqh, aQ, 0, 0, 0);
        aK = __builtin_amdgcn_mfma_f32_16x16x32_bf16(ah, bkh, aK, 0, 0, 0);
        aV = __builtin_amdgcn_mfma_f32_16x16x32_bf16(ah, bvh, aV, 0, 0, 0);
        aQ = __builtin_amdgcn_mfma_f32_16x16x32_bf16(ah, bql, aQ, 0, 0, 0);
        aK = __builtin_amdgcn_mfma_f32_16x16x32_bf16(ah, bkl, aK, 0, 0, 0);
        aQ = __builtin_amdgcn_mfma_f32_16x16x32_bf16(al, bqh, aQ, 0, 0, 0);
        aK = __builtin_amdgcn_mfma_f32_16x16x32_bf16(al, bkh, aK, 0, 0, 0);
    }

    // C/D layout (16x16): col = lane&15, row = (lane>>4)*4 + r  [m89/m91]
    #pragma unroll
    for (int r = 0; r < 4; ++r) {
        int grow = m0 + lk * 4 + r, gcol = n0 + lr;
        float q = aQ[r] * SCALE_LOG2;
        unsigned short hb = f2bf(q);
        Qhi[(size_t)grow * 64 + gcol] = hb;
        Qlo[(size_t)grow * 64 + gcol] = f2bf(q - bf2f(hb));
        float v = aK[r];
        hb = f2bf(v);
        Khi[(size_t)grow * 64 + gcol] = hb;
        Klo[(size_t)grow * 64 + gcol] = f2bf(v - bf2f(hb));
    }
    ushort4 pk;                          // V: 4 consecutive rows -> one 8B store
    pk.x = f2bf(aV[0]); pk.y = f2bf(aV[1]);
    pk.z = f2bf(aV[2]); pk.w = f2bf(aV[3]);
    *(ushort4*)(Vt + (size_t)(n0 + lr) * N_SEQ + m0 + lk * 4) = pk;
}

// ---------------- Kernel 3: flash attention (S^T form + prefetch) ------------
// Round-0 structure (best measured: 56.7us): grid (nsplit, 64); block 256 =
// 4 waves, each wave owns 32 Q-rows; PADK rotation layout (0 conflicts).
// New this round: split-accumulator QK^T (4-deep + 8-deep dependent MFMA
// chains instead of one 12-deep chain) + defer-max + v_perm pack.
__global__ __launch_bounds__(256, 4) void attn(const unsigned short* __restrict__ Qhi,
                                               const unsigned short* __restrict__ Qlo,
                                               const unsigned short* __restrict__ Khi,
                                               const unsigned short* __restrict__ Klo,
                                               const unsigned short* __restrict__ Vt,
                                               float* __restrict__ Opart,
                                               float* __restrict__ mpart,
                                               float* __restrict__ lpart,
                                               int chunk) {
    __shared__ unsigned short sK[128 * PADK];   // rows 0-63 Khi, 64-127 Klo
    __shared__ unsigned short sV [64 * PADK];   // [d][key]

    int tid = threadIdx.x, wv = tid >> 6, lane = tid & 63;
    int lrow = lane & 31, lh = lane >> 5;
    int c = blockIdx.x, qb = blockIdx.y;
    int q0 = qb * 128 + wv * 32;

    // Q fragments (whole D=64) resident in registers
    s16x8 qh[4], ql[4];
    #pragma unroll
    for (int ks = 0; ks < 4; ++ks) {
        int kb = ks * 16 + lh * 8;
        qh[ks] = gfrag(Qhi + (size_t)(q0 + lrow) * 64 + kb);
        ql[ks] = gfrag(Qlo + (size_t)(q0 + lrow) * 64 + kb);
    }

    f32x16 O0, O1;
    #pragma unroll
    for (int i = 0; i < 16; ++i) { O0[i] = 0.f; O1[i] = 0.f; }
    float mrow = -1e30f, lrun = 0.f;

    int steps = chunk >> 6;
    int srow = tid >> 2, sseg = tid & 3;    // staging: 64 rows x 4 segs x 16 elems

    // prefetch tile 0
    uint4 rA0, rA1, rB0, rB1, rC0, rC1;
    {
        int j1 = c * chunk;
        const uint4* ps = (const uint4*)(Khi + ((size_t)(j1 + srow) * 64 + sseg * 16));
        rA0 = ps[0]; rA1 = ps[1];
        ps = (const uint4*)(Klo + ((size_t)(j1 + srow) * 64 + sseg * 16));
        rB0 = ps[0]; rB1 = ps[1];
        ps = (const uint4*)(Vt + ((size_t)srow * N_SEQ + j1 + sseg * 16));
        rC0 = ps[0]; rC1 = ps[1];
    }

    for (int it = 0; it < steps; ++it) {
        __syncthreads();                     // all waves done reading prev tile
        st32(sK + srow * PADK + sseg * 16, rA0, rA1);
        st32(sK + (64 + srow) * PADK + sseg * 16, rB0, rB1);
        st32(sV + srow * PADK + sseg * 16, rC0, rC1);
        __syncthreads();

        if (it + 1 < steps) {                // prefetch next tile (waits at next st32)
            int j1 = c * chunk + (it + 1) * 64;
            const uint4* ps = (const uint4*)(Khi + ((size_t)(j1 + srow) * 64 + sseg * 16));
            rA0 = ps[0]; rA1 = ps[1];
            ps = (const uint4*)(Klo + ((size_t)(j1 + srow) * 64 + sseg * 16));
            rB0 = ps[0]; rB1 = ps[1];
            ps = (const uint4*)(Vt + ((size_t)srow * N_SEQ + j1 + sseg * 16));
            rC0 = ps[0]; rC1 = ps[1];
        }

        // S^T = K @ Q^T, split-bf16 3-term with SPLIT accumulators:
        // sa* holds hi*hi (4-deep chain), sb* holds the cross terms (8-deep).
        f32x16 sa0, sb0, sa1, sb1;
        #pragma unroll
        for (int i = 0; i < 16; ++i) { sa0[i] = 0.f; sb0[i] = 0.f; sa1[i] = 0.f; sb1[i] = 0.f; }
        #pragma unroll
        for (int ks = 0; ks < 4; ++ks) {
            int kb = ks * 16 + lh * 8;
            s16x8 b0h = ldsfrag(sK + (size_t)lrow * PADK + kb);
            s16x8 b0l = ldsfrag(sK + (size_t)(64 + lrow) * PADK + kb);
            sa0 = __builtin_amdgcn_mfma_f32_32x32x16_bf16(b0h, qh[ks], sa0, 0, 0, 0);
            sb0 = __builtin_amdgcn_mfma_f32_32x32x16_bf16(b0l, qh[ks], sb0, 0, 0, 0);
            sb0 = __builtin_amdgcn_mfma_f32_32x32x16_bf16(b0h, ql[ks], sb0, 0, 0, 0);
            s16x8 b1h = ldsfrag(sK + (size_t)(32 + lrow) * PADK + kb);
            s16x8 b1l = ldsfrag(sK + (size_t)(96 + lrow) * PADK + kb);
            sa1 = __builtin_amdgcn_mfma_f32_32x32x16_bf16(b1h, qh[ks], sa1, 0, 0, 0);
            sb1 = __builtin_amdgcn_mfma_f32_32x32x16_bf16(b1l, qh[ks], sb1, 0, 0, 0);
            sb1 = __builtin_amdgcn_mfma_f32_32x32x16_bf16(b1h, ql[ks], sb1, 0, 0, 0);
        }
        f32x16 s0 = sa0 + sb0;
        f32x16 s1 = sa1 + sb1;

        // in-lane row max (4-way tree for ILP)
        float r0 = fmaxf(s0[0], s1[0]), r1 = fmaxf(s0[1], s1[1]);
        float r2 = fmaxf(s0[2], s1[2]), r3 = fmaxf(s0[3], s1[3]);
        #pragma unroll
        for (int i = 4; i < 16; i += 4) {
            r0 = fmaxf(r0, fmaxf(s0[i],     s1[i]));
            r1 = fmaxf(r1, fmaxf(s0[i + 1], s1[i + 1]));
            r2 = fmaxf(r2, fmaxf(s0[i + 2], s1[i + 2]));
            r3 = fmaxf(r3, fmaxf(s0[i + 3], s1[i + 3]));
        }
        float rm = fmaxf(fmaxf(r0, r1), fmaxf(r2, r3));
        rm = fmaxf(rm, __shfl_xor(rm, 32, 64));

        // T13 defer-max: only rescale when the max grew by >8 (P <= 2^8, f32-safe)
        if (__any(rm > mrow + 8.0f)) {
            float mn  = fmaxf(mrow, rm);
            float alf = exp2f(mrow - mn);
            mrow = mn;
            lrun *= alf;
            #pragma unroll
            for (int r = 0; r < 16; ++r) {
                int qr = (r & 3) + 8 * (r >> 2) + 4 * lh;
                float af = __shfl(alf, qr, 64);
                O0[r] *= af; O1[r] *= af;
            }
        }

        // p = exp2(s - m) in place; partial row-sum (4-way tree)
        float p0 = 0.f, p1 = 0.f, p2 = 0.f, p3 = 0.f;
        #pragma unroll
        for (int i = 0; i < 16; i += 4) {
            s0[i]     = exp2f(s0[i] - mrow);     p0 += s0[i];
            s0[i + 1] = exp2f(s0[i + 1] - mrow); p1 += s0[i + 1];
            s0[i + 2] = exp2f(s0[i + 2] - mrow); p2 += s0[i + 2];
            s0[i + 3] = exp2f(s0[i + 3] - mrow); p3 += s0[i + 3];
        }
        #pragma unroll
        for (int i = 0; i < 16; i += 4) {
            s1[i]     = exp2f(s1[i] - mrow);     p0 += s1[i];
            s1[i + 1] = exp2f(s1[i + 1] - mrow); p1 += s1[i + 1];
            s1[i + 2] = exp2f(s1[i + 2] - mrow); p2 += s1[i + 2];
            s1[i + 3] = exp2f(s1[i + 3] - mrow); p3 += s1[i + 3];
        }
        lrun += (p0 + p1) + (p2 + p3);

        // pack P to bf16 pairs (v_perm); swap halves via lane^32 to build A-frags
        unsigned int I[16], J[16];
        #pragma unroll
        for (int q4 = 0; q4 < 4; ++q4) {
            I[2 * q4]     = packbf(s0[4 * q4],     s0[4 * q4 + 1]);
            I[2 * q4 + 1] = packbf(s0[4 * q4 + 2], s0[4 * q4 + 3]);
            I[8 + 2 * q4]     = packbf(s1[4 * q4],     s1[4 * q4 + 1]);
            I[8 + 2 * q4 + 1] = packbf(s1[4 * q4 + 2], s1[4 * q4 + 3]);
        }
        #pragma unroll
        for (int i = 0; i < 16; ++i) J[i] = (unsigned int)__shfl_xor((int)I[i], 32, 64);
        s16x8 a[4];
        #pragma unroll
        for (int ks = 0; ks < 4; ++ks) {
            int b = (ks >> 1) * 8 + (ks & 1) * 4;
            union { unsigned int u[4]; s16x8 s; } fa;
            fa.u[0] = lh ? J[b + 2] : I[b];
            fa.u[1] = lh ? J[b + 3] : I[b + 1];
            fa.u[2] = lh ? I[b + 2] : J[b];
            fa.u[3] = lh ? I[b + 3] : J[b + 1];
            a[ks] = fa.s;
        }

        // O += P @ V
        #pragma unroll
        for (int ks = 0; ks < 4; ++ks) {
            int kb = ks * 16 + lh * 8;
            s16x8 b0 = ldsfrag(sV + (size_t)lrow * PADK + kb);
            s16x8 b1 = ldsfrag(sV + (size_t)(32 + lrow) * PADK + kb);
            O0 = __builtin_amdgcn_mfma_f32_32x32x16_bf16(a[ks], b0, O0, 0, 0, 0);
            O1 = __builtin_amdgcn_mfma_f32_32x32x16_bf16(a[ks], b1, O1, 0, 0, 0);
        }
    }

    // store partials
    #pragma unroll
    for (int r = 0; r < 16; ++r) {
        int row = (r & 3) + 8 * (r >> 2) + 4 * lh;
        int grow = q0 + row;
        size_t ob = ((size_t)c * N_SEQ + grow) * 64;
        Opart[ob + lrow]      = O0[r];
        Opart[ob + 32 + lrow] = O1[r];
    }
    float lfull = lrun + __shfl_xor(lrun, 32, 64);
    if (lane < 32) {
        int grow = q0 + lrow;
        mpart[c * N_SEQ + grow] = mrow;
        lpart[c * N_SEQ + grow] = lfull;
    }
}

// ---------------- Kernel 4: combine split-K partials (float4) ----------------
__global__ __launch_bounds__(256) void combine(const float* __restrict__ Opart,
                                               const float* __restrict__ mpart,
                                               const float* __restrict__ lpart,
                                               float* __restrict__ out,
                                               int nsplit) {
    int idx = blockIdx.x * 256 + threadIdx.x;    // N_SEQ*16
    int row = idx >> 4, d4 = idx & 15;
    float M = -1e30f;
    for (int c = 0; c < nsplit; ++c) M = fmaxf(M, mpart[c * N_SEQ + row]);
    float4 num = make_float4(0.f, 0.f, 0.f, 0.f);
    float den = 0.f;
    for (int c = 0; c < nsplit; ++c) {
        float w = exp2f(mpart[c * N_SEQ + row] - M);
        den += w * lpart[c * N_SEQ + row];
        float4 o = ((const float4*)Opart)[((size_t)c * N_SEQ + row) * 16 + d4];
        num.x += w * o.x; num.y += w * o.y; num.z += w * o.z; num.w += w * o.w;
    }
    float inv = 1.0f / den;
    num.x *= inv; num.y *= inv; num.z *= inv; num.w *= inv;
    ((float4*)out)[idx] = num;
}

extern "C" void kernel_launch(void* const* d_in, const int* in_sizes, int n_in,
                              void* d_out, int out_size, void* d_ws, size_t ws_size,
                              hipStream_t stream) {
    const float* X  = (const float*)d_in[0];
    const float* WQ = (const float*)d_in[1];
    const float* WK = (const float*)d_in[2];
    const float* WV = (const float*)d_in[3];
    float* out = (float*)d_out;

    // workspace carve
    const size_t szQK = (size_t)N_SEQ * 64 * 2;      // 1 MB each (bf16)
    const size_t szW  = (size_t)192 * E_DIM * 2;     // 288 KB each
    const size_t szX  = (size_t)N_SEQ * E_DIM * 2;   // 12.6 MB each (bf16)
    char* p = (char*)d_ws;
    unsigned short* Qhi = (unsigned short*)p; p += szQK;
    unsigned short* Qlo = (unsigned short*)p; p += szQK;
    unsigned short* Khi = (unsigned short*)p; p += szQK;
    unsigned short* Klo = (unsigned short*)p; p += szQK;
    unsigned short* Vt  = (unsigned short*)p; p += szQK;
    unsigned short* Wthi = (unsigned short*)p; p += szW;
    unsigned short* Wtlo = (unsigned short*)p; p += szW;
    unsigned short* Xhi = (unsigned short*)p; p += szX;
    unsigned short* Xlo = (unsigned short*)p; p += szX;
    size_t base = (size_t)(p - (char*)d_ws);
    size_t per  = (size_t)N_SEQ * 64 * 4 + 2 * (size_t)N_SEQ * 4;  // Opart + m + l per split
    int nsplit = 16;
    while (nsplit > 1 && base + (size_t)nsplit * per > ws_size) nsplit >>= 1;
    float* mpart = (float*)p; p += (size_t)nsplit * N_SEQ * 4;
    float* lpart = (float*)p; p += (size_t)nsplit * N_SEQ * 4;
    float* Opart = (float*)p;

    int chunk = N_SEQ / nsplit;

    prep<<<6144 + (192 * E_DIM + 255) / 256, 256, 0, stream>>>(X, WQ, WK, WV,
                                                               Xhi, Xlo, Wthi, Wtlo);
    proj_qkv<<<2048, 64, 0, stream>>>(Xhi, Xlo, Wthi, Wtlo, Qhi, Qlo, Khi, Klo, Vt);
    attn<<<dim3(nsplit, N_SEQ / 128), 256, 0, stream>>>(Qhi, Qlo, Khi, Klo, Vt,
                                                        Opart, mpart, lpart, chunk);
    combine<<<(N_SEQ * 16 + 255) / 256, 256, 0, stream>>>(Opart, mpart, lpart, out, nsplit);
}

// Round 5
// 177.954 us; speedup vs baseline: 1.5553x; 1.5553x over previous
//
#include <hip/hip_runtime.h>
#include <hip/hip_fp16.h>

#define N_SEQ 8192
#define E_DIM 768
#define D_OUT 64
#define PADK 68                       // 64 + 4 pad -> 136B rows: 2-way (free) bank aliasing
#define SCALE_LOG2 0.18033688011112042f   // 1/(8*ln2): fold softmax scale + log2e into Q

typedef __attribute__((ext_vector_type(8)))  short s16x8;
typedef __attribute__((ext_vector_type(4)))  float f32x4;
typedef __attribute__((ext_vector_type(16))) float f32x16;

static __device__ __forceinline__ unsigned short f2bf(float f) {
    union { float f; unsigned int u; } v; v.f = f;
    unsigned int r = v.u + 0x7FFFu + ((v.u >> 16) & 1u);   // RNE
    return (unsigned short)(r >> 16);
}
static __device__ __forceinline__ float bf2f(unsigned short h) {
    union { float f; unsigned int u; } v; v.u = ((unsigned int)h) << 16; return v.f;
}
static __device__ __forceinline__ s16x8 gfrag(const unsigned short* p) {
    union { uint4 u; s16x8 s; } r; r.u = *(const uint4*)p; return r.s;
}
static __device__ __forceinline__ s16x8 ldsfrag(const unsigned short* p) {
    union { uint2 u[2]; s16x8 s; } r;
    r.u[0] = *(const uint2*)(p);
    r.u[1] = *(const uint2*)(p + 4);
    return r.s;
}
// pack two f32 -> bf16x2 by truncation via v_perm (bias cancels: same P feeds O and l)
static __device__ __forceinline__ unsigned int packbf(float a, float b) {
    return __builtin_amdgcn_perm(__float_as_uint(b), __float_as_uint(a), 0x07060302u);
}
static __device__ __forceinline__ void st32(unsigned short* d, uint4 a, uint4 b) {
    uint2* p = (uint2*)d;
    p[0] = make_uint2(a.x, a.y); p[1] = make_uint2(a.z, a.w);
    p[2] = make_uint2(b.x, b.y); p[3] = make_uint2(b.z, b.w);
}

// ---------------- Kernel 1a: W -> Wt (transposed, bf16 hi/lo) ----------------
__global__ __launch_bounds__(256) void prep_w(const float* __restrict__ WQ,
                                              const float* __restrict__ WK,
                                              const float* __restrict__ WV,
                                              unsigned short* __restrict__ Wthi,
                                              unsigned short* __restrict__ Wtlo) {
    int idx = blockIdx.x * 256 + threadIdx.x;          // 192*768 total
    if (idx >= 192 * E_DIM) return;
    int n = idx / E_DIM;
    int k = idx - n * E_DIM;
    float v;
    if (n < 64)       v = WQ[k * 64 + n];
    else if (n < 128) v = WK[k * 64 + (n - 64)];
    else              v = WV[k * 64 + (n - 128)];
    unsigned short hb = f2bf(v);
    Wthi[idx] = hb;
    Wtlo[idx] = f2bf(v - bf2f(hb));
}

// ---------------- Kernel 1b: X -> bf16 hi/lo (coalesced, BW-bound) -----------
__global__ __launch_bounds__(256) void prep_x(const float* __restrict__ X,
                                              unsigned short* __restrict__ Xhi,
                                              unsigned short* __restrict__ Xlo) {
    int idx = blockIdx.x * 256 + threadIdx.x;          // over float4: 8192*768/4
    float4 v = ((const float4*)X)[idx];
    ushort4 hi, lo;
    hi.x = f2bf(v.x); lo.x = f2bf(v.x - bf2f(hi.x));
    hi.y = f2bf(v.y); lo.y = f2bf(v.y - bf2f(hi.y));
    hi.z = f2bf(v.z); lo.z = f2bf(v.z - bf2f(hi.z));
    hi.w = f2bf(v.w); lo.w = f2bf(v.w - bf2f(hi.w));
    ((ushort4*)Xhi)[idx] = hi;
    ((ushort4*)Xlo)[idx] = lo;
}

// ---------------- Kernel 2: QKV projection (fused Q/K/V per wave) ------------
__global__ __launch_bounds__(256, 4) void proj_qkv(const unsigned short* __restrict__ Xhi,
                                                   const unsigned short* __restrict__ Xlo,
                                                   const unsigned short* __restrict__ Wthi,
                                                   const unsigned short* __restrict__ Wtlo,
                                                   unsigned short* __restrict__ Qhi,
                                                   unsigned short* __restrict__ Qlo,
                                                   unsigned short* __restrict__ Khi,
                                                   unsigned short* __restrict__ Klo,
                                                   unsigned short* __restrict__ Vt) {
    int tid  = threadIdx.x;
    int wv   = tid >> 6;
    int lane = tid & 63;
    int id   = blockIdx.x * 4 + wv;          // 0..2047
    int mt   = id >> 2;
    int c    = id & 3;                       // 16-col block within D=64
    int m0 = mt * 16, n0 = c * 16;
    int lr = lane & 15, lk = lane >> 4;      // row-in-tile, k-quad

    f32x4 aQ, aK, aV;
    #pragma unroll
    for (int i = 0; i < 4; ++i) { aQ[i] = 0.f; aK[i] = 0.f; aV[i] = 0.f; }

    const unsigned short* xh  = Xhi  + (size_t)(m0 + lr) * E_DIM + lk * 8;
    const unsigned short* xl  = Xlo  + (size_t)(m0 + lr) * E_DIM + lk * 8;
    const unsigned short* wqh = Wthi + (size_t)(n0 + lr) * E_DIM + lk * 8;
    const unsigned short* wql = Wtlo + (size_t)(n0 + lr) * E_DIM + lk * 8;
    const unsigned short* wkh = Wthi + (size_t)(64 + n0 + lr) * E_DIM + lk * 8;
    const unsigned short* wkl = Wtlo + (size_t)(64 + n0 + lr) * E_DIM + lk * 8;
    const unsigned short* wvh = Wthi + (size_t)(128 + n0 + lr) * E_DIM + lk * 8;

    #pragma unroll 2
    for (int ks = 0; ks < E_DIM / 32; ++ks) {
        int kb = ks * 32;
        s16x8 ah = gfrag(xh + kb);
        s16x8 al = gfrag(xl + kb);
        s16x8 bqh = gfrag(wqh + kb);
        s16x8 bql = gfrag(wql + kb);
        s16x8 bkh = gfrag(wkh + kb);
        s16x8 bkl = gfrag(wkl + kb);
        s16x8 bvh = gfrag(wvh + kb);
        aQ = __builtin_amdgcn_mfma_f32_16x16x32_bf16(ah, bqh, aQ, 0, 0, 0);
        aK = __builtin_amdgcn_mfma_f32_16x16x32_bf16(ah, bkh, aK, 0, 0, 0);
        aV = __builtin_amdgcn_mfma_f32_16x16x32_bf16(ah, bvh, aV, 0, 0, 0);
        aQ = __builtin_amdgcn_mfma_f32_16x16x32_bf16(ah, bql, aQ, 0, 0, 0);
        aK = __builtin_amdgcn_mfma_f32_16x16x32_bf16(ah, bkl, aK, 0, 0, 0);
        aQ = __builtin_amdgcn_mfma_f32_16x16x32_bf16(al, bqh, aQ, 0, 0, 0);
        aK = __builtin_amdgcn_mfma_f32_16x16x32_bf16(al, bkh, aK, 0, 0, 0);
    }

    // C/D layout (16x16): col = lane&15, row = (lane>>4)*4 + r  [m89/m91]
    #pragma unroll
    for (int r = 0; r < 4; ++r) {
        int grow = m0 + lk * 4 + r, gcol = n0 + lr;
        float q = aQ[r] * SCALE_LOG2;
        unsigned short hb = f2bf(q);
        Qhi[(size_t)grow * 64 + gcol] = hb;
        Qlo[(size_t)grow * 64 + gcol] = f2bf(q - bf2f(hb));
        float v = aK[r];
        hb = f2bf(v);
        Khi[(size_t)grow * 64 + gcol] = hb;
        Klo[(size_t)grow * 64 + gcol] = f2bf(v - bf2f(hb));
    }
    ushort4 pk;                          // V: 4 consecutive rows -> one 8B store
    pk.x = f2bf(aV[0]); pk.y = f2bf(aV[1]);
    pk.z = f2bf(aV[2]); pk.w = f2bf(aV[3]);
    *(ushort4*)(Vt + (size_t)(n0 + lr) * N_SEQ + m0 + lk * 4) = pk;
}

// ---------------- Kernel 3: flash attention (S^T form + prefetch) ------------
// Round-0 structure (best measured: 56.7us): grid (nsplit, 64); block 256 =
// 4 waves x 32 Q-rows; PADK rotation layout (0 conflicts); reg prefetch.
// Deltas this round (both correctness-verified in earlier rounds / low-risk):
//  - T13 defer-max: skip O-rescale unless running max grew by >8 log2 units
//  - T5 s_setprio(1) around the two MFMA clusters (m191: +4-7% attn regime)
__global__ __launch_bounds__(256, 3) void attn(const unsigned short* __restrict__ Qhi,
                                               const unsigned short* __restrict__ Qlo,
                                               const unsigned short* __restrict__ Khi,
                                               const unsigned short* __restrict__ Klo,
                                               const unsigned short* __restrict__ Vt,
                                               float* __restrict__ Opart,
                                               float* __restrict__ mpart,
                                               float* __restrict__ lpart,
                                               int chunk) {
    __shared__ unsigned short sK[128 * PADK];   // rows 0-63 Khi, 64-127 Klo
    __shared__ unsigned short sV [64 * PADK];   // [d][key]

    int tid = threadIdx.x, wv = tid >> 6, lane = tid & 63;
    int lrow = lane & 31, lh = lane >> 5;
    int c = blockIdx.x, qb = blockIdx.y;
    int q0 = qb * 128 + wv * 32;

    // Q fragments (whole D=64) resident in registers
    s16x8 qh[4], ql[4];
    #pragma unroll
    for (int ks = 0; ks < 4; ++ks) {
        int kb = ks * 16 + lh * 8;
        qh[ks] = gfrag(Qhi + (size_t)(q0 + lrow) * 64 + kb);
        ql[ks] = gfrag(Qlo + (size_t)(q0 + lrow) * 64 + kb);
    }

    f32x16 O0, O1;
    #pragma unroll
    for (int i = 0; i < 16; ++i) { O0[i] = 0.f; O1[i] = 0.f; }
    float mrow = -1e30f, lrun = 0.f;

    int steps = chunk >> 6;
    int srow = tid >> 2, sseg = tid & 3;    // staging: 64 rows x 4 segs x 16 elems

    // prefetch tile 0
    uint4 rA0, rA1, rB0, rB1, rC0, rC1;
    {
        int j1 = c * chunk;
        const uint4* ps = (const uint4*)(Khi + ((size_t)(j1 + srow) * 64 + sseg * 16));
        rA0 = ps[0]; rA1 = ps[1];
        ps = (const uint4*)(Klo + ((size_t)(j1 + srow) * 64 + sseg * 16));
        rB0 = ps[0]; rB1 = ps[1];
        ps = (const uint4*)(Vt + ((size_t)srow * N_SEQ + j1 + sseg * 16));
        rC0 = ps[0]; rC1 = ps[1];
    }

    for (int it = 0; it < steps; ++it) {
        __syncthreads();                     // all waves done reading prev tile
        st32(sK + srow * PADK + sseg * 16, rA0, rA1);
        st32(sK + (64 + srow) * PADK + sseg * 16, rB0, rB1);
        st32(sV + srow * PADK + sseg * 16, rC0, rC1);
        __syncthreads();

        if (it + 1 < steps) {                // prefetch next tile (waits at next st32)
            int j1 = c * chunk + (it + 1) * 64;
            const uint4* ps = (const uint4*)(Khi + ((size_t)(j1 + srow) * 64 + sseg * 16));
            rA0 = ps[0]; rA1 = ps[1];
            ps = (const uint4*)(Klo + ((size_t)(j1 + srow) * 64 + sseg * 16));
            rB0 = ps[0]; rB1 = ps[1];
            ps = (const uint4*)(Vt + ((size_t)srow * N_SEQ + j1 + sseg * 16));
            rC0 = ps[0]; rC1 = ps[1];
        }

        // S^T = K @ Q^T  (3-term split-bf16): s0 keys 0-31, s1 keys 32-63
        f32x16 s0, s1;
        #pragma unroll
        for (int i = 0; i < 16; ++i) { s0[i] = 0.f; s1[i] = 0.f; }
        __builtin_amdgcn_s_setprio(1);
        #pragma unroll
        for (int ks = 0; ks < 4; ++ks) {
            int kb = ks * 16 + lh * 8;
            s16x8 b0h = ldsfrag(sK + (size_t)lrow * PADK + kb);
            s16x8 b0l = ldsfrag(sK + (size_t)(64 + lrow) * PADK + kb);
            s0 = __builtin_amdgcn_mfma_f32_32x32x16_bf16(b0h, qh[ks], s0, 0, 0, 0);
            s0 = __builtin_amdgcn_mfma_f32_32x32x16_bf16(b0l, qh[ks], s0, 0, 0, 0);
            s0 = __builtin_amdgcn_mfma_f32_32x32x16_bf16(b0h, ql[ks], s0, 0, 0, 0);
            s16x8 b1h = ldsfrag(sK + (size_t)(32 + lrow) * PADK + kb);
            s16x8 b1l = ldsfrag(sK + (size_t)(96 + lrow) * PADK + kb);
            s1 = __builtin_amdgcn_mfma_f32_32x32x16_bf16(b1h, qh[ks], s1, 0, 0, 0);
            s1 = __builtin_amdgcn_mfma_f32_32x32x16_bf16(b1l, qh[ks], s1, 0, 0, 0);
            s1 = __builtin_amdgcn_mfma_f32_32x32x16_bf16(b1h, ql[ks], s1, 0, 0, 0);
        }
        __builtin_amdgcn_s_setprio(0);

        // in-lane row max (4-way tree for ILP)
        float r0 = fmaxf(s0[0], s1[0]), r1 = fmaxf(s0[1], s1[1]);
        float r2 = fmaxf(s0[2], s1[2]), r3 = fmaxf(s0[3], s1[3]);
        #pragma unroll
        for (int i = 4; i < 16; i += 4) {
            r0 = fmaxf(r0, fmaxf(s0[i],     s1[i]));
            r1 = fmaxf(r1, fmaxf(s0[i + 1], s1[i + 1]));
            r2 = fmaxf(r2, fmaxf(s0[i + 2], s1[i + 2]));
            r3 = fmaxf(r3, fmaxf(s0[i + 3], s1[i + 3]));
        }
        float rm = fmaxf(fmaxf(r0, r1), fmaxf(r2, r3));
        rm = fmaxf(rm, __shfl_xor(rm, 32, 64));

        // T13 defer-max: only rescale when the max grew by >8 (P <= 2^8, f32-safe)
        if (__any(rm > mrow + 8.0f)) {
            float mn  = fmaxf(mrow, rm);
            float alf = exp2f(mrow - mn);
            mrow = mn;
            lrun *= alf;
            #pragma unroll
            for (int r = 0; r < 16; ++r) {
                int qr = (r & 3) + 8 * (r >> 2) + 4 * lh;
                float af = __shfl(alf, qr, 64);
                O0[r] *= af; O1[r] *= af;
            }
        }

        // p = exp2(s - m) in place; partial row-sum (4-way tree)
        float p0 = 0.f, p1 = 0.f, p2 = 0.f, p3 = 0.f;
        #pragma unroll
        for (int i = 0; i < 16; i += 4) {
            s0[i]     = exp2f(s0[i] - mrow);     p0 += s0[i];
            s0[i + 1] = exp2f(s0[i + 1] - mrow); p1 += s0[i + 1];
            s0[i + 2] = exp2f(s0[i + 2] - mrow); p2 += s0[i + 2];
            s0[i + 3] = exp2f(s0[i + 3] - mrow); p3 += s0[i + 3];
        }
        #pragma unroll
        for (int i = 0; i < 16; i += 4) {
            s1[i]     = exp2f(s1[i] - mrow);     p0 += s1[i];
            s1[i + 1] = exp2f(s1[i + 1] - mrow); p1 += s1[i + 1];
            s1[i + 2] = exp2f(s1[i + 2] - mrow); p2 += s1[i + 2];
            s1[i + 3] = exp2f(s1[i + 3] - mrow); p3 += s1[i + 3];
        }
        lrun += (p0 + p1) + (p2 + p3);

        // pack P to bf16 pairs (v_perm); swap halves via lane^32 to build A-frags
        unsigned int I[16], J[16];
        #pragma unroll
        for (int q4 = 0; q4 < 4; ++q4) {
            I[2 * q4]     = packbf(s0[4 * q4],     s0[4 * q4 + 1]);
            I[2 * q4 + 1] = packbf(s0[4 * q4 + 2], s0[4 * q4 + 3]);
            I[8 + 2 * q4]     = packbf(s1[4 * q4],     s1[4 * q4 + 1]);
            I[8 + 2 * q4 + 1] = packbf(s1[4 * q4 + 2], s1[4 * q4 + 3]);
        }
        #pragma unroll
        for (int i = 0; i < 16; ++i) J[i] = (unsigned int)__shfl_xor((int)I[i], 32, 64);
        s16x8 a[4];
        #pragma unroll
        for (int ks = 0; ks < 4; ++ks) {
            int b = (ks >> 1) * 8 + (ks & 1) * 4;
            union { unsigned int u[4]; s16x8 s; } fa;
            fa.u[0] = lh ? J[b + 2] : I[b];
            fa.u[1] = lh ? J[b + 3] : I[b + 1];
            fa.u[2] = lh ? I[b + 2] : J[b];
            fa.u[3] = lh ? I[b + 3] : J[b + 1];
            a[ks] = fa.s;
        }

        // O += P @ V
        __builtin_amdgcn_s_setprio(1);
        #pragma unroll
        for (int ks = 0; ks < 4; ++ks) {
            int kb = ks * 16 + lh * 8;
            s16x8 b0 = ldsfrag(sV + (size_t)lrow * PADK + kb);
            s16x8 b1 = ldsfrag(sV + (size_t)(32 + lrow) * PADK + kb);
            O0 = __builtin_amdgcn_mfma_f32_32x32x16_bf16(a[ks], b0, O0, 0, 0, 0);
            O1 = __builtin_amdgcn_mfma_f32_32x32x16_bf16(a[ks], b1, O1, 0, 0, 0);
        }
        __builtin_amdgcn_s_setprio(0);
    }

    // store partials
    #pragma unroll
    for (int r = 0; r < 16; ++r) {
        int row = (r & 3) + 8 * (r >> 2) + 4 * lh;
        int grow = q0 + row;
        size_t ob = ((size_t)c * N_SEQ + grow) * 64;
        Opart[ob + lrow]      = O0[r];
        Opart[ob + 32 + lrow] = O1[r];
    }
    float lfull = lrun + __shfl_xor(lrun, 32, 64);
    if (lane < 32) {
        int grow = q0 + lrow;
        mpart[c * N_SEQ + grow] = mrow;
        lpart[c * N_SEQ + grow] = lfull;
    }
}

// ---------------- Kernel 4: combine split-K partials (float4) ----------------
__global__ __launch_bounds__(256) void combine(const float* __restrict__ Opart,
                                               const float* __restrict__ mpart,
                                               const float* __restrict__ lpart,
                                               float* __restrict__ out,
                                               int nsplit) {
    int idx = blockIdx.x * 256 + threadIdx.x;    // N_SEQ*16
    int row = idx >> 4, d4 = idx & 15;
    float M = -1e30f;
    for (int c = 0; c < nsplit; ++c) M = fmaxf(M, mpart[c * N_SEQ + row]);
    float4 num = make_float4(0.f, 0.f, 0.f, 0.f);
    float den = 0.f;
    for (int c = 0; c < nsplit; ++c) {
        float w = exp2f(mpart[c * N_SEQ + row] - M);
        den += w * lpart[c * N_SEQ + row];
        float4 o = ((const float4*)Opart)[((size_t)c * N_SEQ + row) * 16 + d4];
        num.x += w * o.x; num.y += w * o.y; num.z += w * o.z; num.w += w * o.w;
    }
    float inv = 1.0f / den;
    num.x *= inv; num.y *= inv; num.z *= inv; num.w *= inv;
    ((float4*)out)[idx] = num;
}

extern "C" void kernel_launch(void* const* d_in, const int* in_sizes, int n_in,
                              void* d_out, int out_size, void* d_ws, size_t ws_size,
                              hipStream_t stream) {
    const float* X  = (const float*)d_in[0];
    const float* WQ = (const float*)d_in[1];
    const float* WK = (const float*)d_in[2];
    const float* WV = (const float*)d_in[3];
    float* out = (float*)d_out;

    // workspace carve
    const size_t szQK = (size_t)N_SEQ * 64 * 2;      // 1 MB each (bf16)
    const size_t szW  = (size_t)192 * E_DIM * 2;     // 288 KB each
    const size_t szX  = (size_t)N_SEQ * E_DIM * 2;   // 12.6 MB each (bf16)
    char* p = (char*)d_ws;
    unsigned short* Qhi = (unsigned short*)p; p += szQK;
    unsigned short* Qlo = (unsigned short*)p; p += szQK;
    unsigned short* Khi = (unsigned short*)p; p += szQK;
    unsigned short* Klo = (unsigned short*)p; p += szQK;
    unsigned short* Vt  = (unsigned short*)p; p += szQK;
    unsigned short* Wthi = (unsigned short*)p; p += szW;
    unsigned short* Wtlo = (unsigned short*)p; p += szW;
    unsigned short* Xhi = (unsigned short*)p; p += szX;
    unsigned short* Xlo = (unsigned short*)p; p += szX;
    size_t base = (size_t)(p - (char*)d_ws);
    size_t per  = (size_t)N_SEQ * 64 * 4 + 2 * (size_t)N_SEQ * 4;  // Opart + m + l per split
    int nsplit = 16;
    while (nsplit > 1 && base + (size_t)nsplit * per > ws_size) nsplit >>= 1;
    float* mpart = (float*)p; p += (size_t)nsplit * N_SEQ * 4;
    float* lpart = (float*)p; p += (size_t)nsplit * N_SEQ * 4;
    float* Opart = (float*)p;

    int chunk = N_SEQ / nsplit;

    prep_w<<<(192 * E_DIM + 255) / 256, 256, 0, stream>>>(WQ, WK, WV, Wthi, Wtlo);
    prep_x<<<(N_SEQ * E_DIM / 4) / 256, 256, 0, stream>>>(X, Xhi, Xlo);
    proj_qkv<<<512, 256, 0, stream>>>(Xhi, Xlo, Wthi, Wtlo, Qhi, Qlo, Khi, Klo, Vt);
    attn<<<dim3(nsplit, N_SEQ / 128), 256, 0, stream>>>(Qhi, Qlo, Khi, Klo, Vt,
                                                        Opart, mpart, lpart, chunk);
    combine<<<(N_SEQ * 16 + 255) / 256, 256, 0, stream>>>(Opart, mpart, lpart, out, nsplit);
}

// Round 6
// 167.436 us; speedup vs baseline: 1.6530x; 1.0628x over previous
//
#include <hip/hip_runtime.h>
#include <hip/hip_fp16.h>

#define N_SEQ 8192
#define E_DIM 768
#define D_OUT 64
#define PADK 68                       // 64 + 4 pad -> 136B rows: 2-way (free) bank aliasing
#define SCALE_LOG2 0.18033688011112042f   // 1/(8*ln2): fold softmax scale + log2e into Q

typedef __attribute__((ext_vector_type(8)))  short s16x8;
typedef __attribute__((ext_vector_type(4)))  float f32x4;
typedef __attribute__((ext_vector_type(16))) float f32x16;

static __device__ __forceinline__ unsigned short f2bf(float f) {
    union { float f; unsigned int u; } v; v.f = f;
    unsigned int r = v.u + 0x7FFFu + ((v.u >> 16) & 1u);   // RNE
    return (unsigned short)(r >> 16);
}
static __device__ __forceinline__ float bf2f(unsigned short h) {
    union { float f; unsigned int u; } v; v.u = ((unsigned int)h) << 16; return v.f;
}
// pack two f32 -> bf16x2 by truncation (bias cancels: same P feeds O and l)
static __device__ __forceinline__ unsigned int packbf(float a, float b) {
    union { float f; unsigned int u; } x, y; x.f = a; y.f = b;
    return (y.u & 0xFFFF0000u) | (x.u >> 16);
}
static __device__ __forceinline__ s16x8 gfrag(const unsigned short* p) {
    union { uint4 u; s16x8 s; } r; r.u = *(const uint4*)p; return r.s;
}
static __device__ __forceinline__ s16x8 ldsfrag(const unsigned short* p) {
    union { uint2 u[2]; s16x8 s; } r;
    r.u[0] = *(const uint2*)(p);
    r.u[1] = *(const uint2*)(p + 4);
    return r.s;
}
static __device__ __forceinline__ void st32(unsigned short* d, uint4 a, uint4 b) {
    uint2* p = (uint2*)d;
    p[0] = make_uint2(a.x, a.y); p[1] = make_uint2(a.z, a.w);
    p[2] = make_uint2(b.x, b.y); p[3] = make_uint2(b.z, b.w);
}

// ---------------- Kernel 1: W -> Wt (transposed, bf16 hi/lo) -----------------
__global__ __launch_bounds__(256) void prep_w(const float* __restrict__ WQ,
                                              const float* __restrict__ WK,
                                              const float* __restrict__ WV,
                                              unsigned short* __restrict__ Wthi,
                                              unsigned short* __restrict__ Wtlo) {
    int idx = blockIdx.x * 256 + threadIdx.x;          // 192*768 total
    if (idx >= 192 * E_DIM) return;
    int n = idx / E_DIM;
    int k = idx - n * E_DIM;
    float v;
    if (n < 64)       v = WQ[k * 64 + n];
    else if (n < 128) v = WK[k * 64 + (n - 64)];
    else              v = WV[k * 64 + (n - 128)];
    unsigned short hb = f2bf(v);
    Wthi[idx] = hb;
    Wtlo[idx] = f2bf(v - bf2f(hb));
}

// ---------------- Kernel 2: QKV projection (X f32 in, convert in-reg) --------
// prep_x is gone: X is read as f32 (same bytes/elem as the old hi+lo bf16 pair)
// and split to hi/lo bf16 fragments in registers -- bit-identical to the old
// prep_x output, so Q/K/V results are unchanged. Saves the 50MB Xhi/Xlo
// round-trip plus one kernel launch. Waves here are load-latency-bound with
// idle VALU; conversion (~56 VALU/kstep) hides under the loads.
__global__ __launch_bounds__(256, 2) void proj_qkv(const float* __restrict__ X,
                                                   const unsigned short* __restrict__ Wthi,
                                                   const unsigned short* __restrict__ Wtlo,
                                                   unsigned short* __restrict__ Qhi,
                                                   unsigned short* __restrict__ Qlo,
                                                   unsigned short* __restrict__ Khi,
                                                   unsigned short* __restrict__ Klo,
                                                   unsigned short* __restrict__ Vt) {
    int tid  = threadIdx.x;
    int wv   = tid >> 6;
    int lane = tid & 63;
    int id   = blockIdx.x * 4 + wv;          // 0..2047
    int mt   = id >> 2;
    int c    = id & 3;                       // 16-col block within D=64
    int m0 = mt * 16, n0 = c * 16;
    int lr = lane & 15, lk = lane >> 4;      // row-in-tile, k-quad

    f32x4 aQ, aK, aV;
    #pragma unroll
    for (int i = 0; i < 4; ++i) { aQ[i] = 0.f; aK[i] = 0.f; aV[i] = 0.f; }

    const float*          xp  = X    + (size_t)(m0 + lr) * E_DIM + lk * 8;
    const unsigned short* wqh = Wthi + (size_t)(n0 + lr) * E_DIM + lk * 8;
    const unsigned short* wql = Wtlo + (size_t)(n0 + lr) * E_DIM + lk * 8;
    const unsigned short* wkh = Wthi + (size_t)(64 + n0 + lr) * E_DIM + lk * 8;
    const unsigned short* wkl = Wtlo + (size_t)(64 + n0 + lr) * E_DIM + lk * 8;
    const unsigned short* wvh = Wthi + (size_t)(128 + n0 + lr) * E_DIM + lk * 8;

    #pragma unroll 2
    for (int ks = 0; ks < E_DIM / 32; ++ks) {
        int kb = ks * 32;
        float4 x0 = *(const float4*)(xp + kb);
        float4 x1 = *(const float4*)(xp + kb + 4);
        s16x8 bqh = gfrag(wqh + kb);
        s16x8 bql = gfrag(wql + kb);
        s16x8 bkh = gfrag(wkh + kb);
        s16x8 bkl = gfrag(wkl + kb);
        s16x8 bvh = gfrag(wvh + kb);
        // split X f32 -> hi/lo bf16 fragments (bit-identical to old prep_x)
        float xs[8] = { x0.x, x0.y, x0.z, x0.w, x1.x, x1.y, x1.z, x1.w };
        union { unsigned short u[8]; s16x8 s; } ah, al;
        #pragma unroll
        for (int i = 0; i < 8; ++i) {
            unsigned short hb = f2bf(xs[i]);
            ah.u[i] = hb;
            al.u[i] = f2bf(xs[i] - bf2f(hb));
        }
        aQ = __builtin_amdgcn_mfma_f32_16x16x32_bf16(ah.s, bqh, aQ, 0, 0, 0);
        aK = __builtin_amdgcn_mfma_f32_16x16x32_bf16(ah.s, bkh, aK, 0, 0, 0);
        aV = __builtin_amdgcn_mfma_f32_16x16x32_bf16(ah.s, bvh, aV, 0, 0, 0);
        aQ = __builtin_amdgcn_mfma_f32_16x16x32_bf16(ah.s, bql, aQ, 0, 0, 0);
        aK = __builtin_amdgcn_mfma_f32_16x16x32_bf16(ah.s, bkl, aK, 0, 0, 0);
        aQ = __builtin_amdgcn_mfma_f32_16x16x32_bf16(al.s, bqh, aQ, 0, 0, 0);
        aK = __builtin_amdgcn_mfma_f32_16x16x32_bf16(al.s, bkh, aK, 0, 0, 0);
    }

    // C/D layout (16x16): col = lane&15, row = (lane>>4)*4 + r  [m89/m91]
    #pragma unroll
    for (int r = 0; r < 4; ++r) {
        int grow = m0 + lk * 4 + r, gcol = n0 + lr;
        float q = aQ[r] * SCALE_LOG2;
        unsigned short hb = f2bf(q);
        Qhi[(size_t)grow * 64 + gcol] = hb;
        Qlo[(size_t)grow * 64 + gcol] = f2bf(q - bf2f(hb));
        float v = aK[r];
        hb = f2bf(v);
        Khi[(size_t)grow * 64 + gcol] = hb;
        Klo[(size_t)grow * 64 + gcol] = f2bf(v - bf2f(hb));
    }
    ushort4 pk;                          // V: 4 consecutive rows -> one 8B store
    pk.x = f2bf(aV[0]); pk.y = f2bf(aV[1]);
    pk.z = f2bf(aV[2]); pk.w = f2bf(aV[3]);
    *(ushort4*)(Vt + (size_t)(n0 + lr) * N_SEQ + m0 + lk * 4) = pk;
}

// ---------------- Kernel 3: flash attention (round-0 verbatim, 56.7us) ------
// grid (nsplit, 64); block 256 = 4 waves, each wave owns 32 Q-rows.
// S^T = K*Q^T so each query's scores are in-lane: scalar m/l, in-lane max,
// P -> A-frags via lane^32 swap (no LDS round-trip). K/V global loads for
// iter i+1 prefetched into registers during iter i's compute phase.
__global__ __launch_bounds__(256, 3) void attn(const unsigned short* __restrict__ Qhi,
                                               const unsigned short* __restrict__ Qlo,
                                               const unsigned short* __restrict__ Khi,
                                               const unsigned short* __restrict__ Klo,
                                               const unsigned short* __restrict__ Vt,
                                               float* __restrict__ Opart,
                                               float* __restrict__ mpart,
                                               float* __restrict__ lpart,
                                               int chunk) {
    __shared__ unsigned short sK[128 * PADK];   // rows 0-63 Khi, 64-127 Klo
    __shared__ unsigned short sV [64 * PADK];   // [d][key]

    int tid = threadIdx.x, wv = tid >> 6, lane = tid & 63;
    int lrow = lane & 31, lh = lane >> 5;
    int c = blockIdx.x, qb = blockIdx.y;
    int q0 = qb * 128 + wv * 32;

    // Q fragments (whole D=64) resident in registers
    s16x8 qh[4], ql[4];
    #pragma unroll
    for (int ks = 0; ks < 4; ++ks) {
        int kb = ks * 16 + lh * 8;
        qh[ks] = gfrag(Qhi + (size_t)(q0 + lrow) * 64 + kb);
        ql[ks] = gfrag(Qlo + (size_t)(q0 + lrow) * 64 + kb);
    }

    f32x16 O0, O1;
    #pragma unroll
    for (int i = 0; i < 16; ++i) { O0[i] = 0.f; O1[i] = 0.f; }
    float mrow = -1e30f, lrun = 0.f;

    int steps = chunk >> 6;
    int srow = tid >> 2, sseg = tid & 3;    // staging: 64 rows x 4 segs x 16 elems

    // prefetch tile 0
    uint4 rA0, rA1, rB0, rB1, rC0, rC1;
    {
        int j1 = c * chunk;
        const uint4* ps = (const uint4*)(Khi + ((size_t)(j1 + srow) * 64 + sseg * 16));
        rA0 = ps[0]; rA1 = ps[1];
        ps = (const uint4*)(Klo + ((size_t)(j1 + srow) * 64 + sseg * 16));
        rB0 = ps[0]; rB1 = ps[1];
        ps = (const uint4*)(Vt + ((size_t)srow * N_SEQ + j1 + sseg * 16));
        rC0 = ps[0]; rC1 = ps[1];
    }

    for (int it = 0; it < steps; ++it) {
        __syncthreads();                     // all waves done reading prev tile
        st32(sK + srow * PADK + sseg * 16, rA0, rA1);
        st32(sK + (64 + srow) * PADK + sseg * 16, rB0, rB1);
        st32(sV + srow * PADK + sseg * 16, rC0, rC1);
        __syncthreads();

        if (it + 1 < steps) {                // prefetch next tile (waits at next st32)
            int j1 = c * chunk + (it + 1) * 64;
            const uint4* ps = (const uint4*)(Khi + ((size_t)(j1 + srow) * 64 + sseg * 16));
            rA0 = ps[0]; rA1 = ps[1];
            ps = (const uint4*)(Klo + ((size_t)(j1 + srow) * 64 + sseg * 16));
            rB0 = ps[0]; rB1 = ps[1];
            ps = (const uint4*)(Vt + ((size_t)srow * N_SEQ + j1 + sseg * 16));
            rC0 = ps[0]; rC1 = ps[1];
        }

        // S^T = K @ Q^T  (3-term split-bf16): s0 keys 0-31, s1 keys 32-63
        f32x16 s0, s1;
        #pragma unroll
        for (int i = 0; i < 16; ++i) { s0[i] = 0.f; s1[i] = 0.f; }
        #pragma unroll
        for (int ks = 0; ks < 4; ++ks) {
            int kb = ks * 16 + lh * 8;
            s16x8 b0h = ldsfrag(sK + (size_t)lrow * PADK + kb);
            s16x8 b0l = ldsfrag(sK + (size_t)(64 + lrow) * PADK + kb);
            s0 = __builtin_amdgcn_mfma_f32_32x32x16_bf16(b0h, qh[ks], s0, 0, 0, 0);
            s0 = __builtin_amdgcn_mfma_f32_32x32x16_bf16(b0l, qh[ks], s0, 0, 0, 0);
            s0 = __builtin_amdgcn_mfma_f32_32x32x16_bf16(b0h, ql[ks], s0, 0, 0, 0);
            s16x8 b1h = ldsfrag(sK + (size_t)(32 + lrow) * PADK + kb);
            s16x8 b1l = ldsfrag(sK + (size_t)(96 + lrow) * PADK + kb);
            s1 = __builtin_amdgcn_mfma_f32_32x32x16_bf16(b1h, qh[ks], s1, 0, 0, 0);
            s1 = __builtin_amdgcn_mfma_f32_32x32x16_bf16(b1l, qh[ks], s1, 0, 0, 0);
            s1 = __builtin_amdgcn_mfma_f32_32x32x16_bf16(b1h, ql[ks], s1, 0, 0, 0);
        }

        // in-lane row max (this lane's query = lrow; 32 of 64 keys per half)
        float rm = s0[0];
        #pragma unroll
        for (int i = 1; i < 16; ++i) rm = fmaxf(rm, s0[i]);
        #pragma unroll
        for (int i = 0; i < 16; ++i) rm = fmaxf(rm, s1[i]);
        rm = fmaxf(rm, __shfl_xor(rm, 32, 64));
        float mn  = fmaxf(mrow, rm);
        float alf = exp2f(mrow - mn);
        mrow = mn;

        // p = exp2(s - m) in place; partial row-sum
        float psum = 0.f;
        #pragma unroll
        for (int i = 0; i < 16; ++i) { s0[i] = exp2f(s0[i] - mn); psum += s0[i]; }
        #pragma unroll
        for (int i = 0; i < 16; ++i) { s1[i] = exp2f(s1[i] - mn); psum += s1[i]; }
        lrun = lrun * alf + psum;

        // pack P to bf16 pairs; swap halves via lane^32 to build A-frags
        unsigned int I[16], J[16];
        #pragma unroll
        for (int q4 = 0; q4 < 4; ++q4) {
            I[2 * q4]     = packbf(s0[4 * q4],     s0[4 * q4 + 1]);
            I[2 * q4 + 1] = packbf(s0[4 * q4 + 2], s0[4 * q4 + 3]);
            I[8 + 2 * q4]     = packbf(s1[4 * q4],     s1[4 * q4 + 1]);
            I[8 + 2 * q4 + 1] = packbf(s1[4 * q4 + 2], s1[4 * q4 + 3]);
        }
        #pragma unroll
        for (int i = 0; i < 16; ++i) J[i] = (unsigned int)__shfl_xor((int)I[i], 32, 64);
        s16x8 a[4];
        #pragma unroll
        for (int ks = 0; ks < 4; ++ks) {
            int b = (ks >> 1) * 8 + (ks & 1) * 4;
            union { unsigned int u[4]; s16x8 s; } fa;
            fa.u[0] = lh ? J[b + 2] : I[b];
            fa.u[1] = lh ? J[b + 3] : I[b + 1];
            fa.u[2] = lh ? I[b + 2] : J[b];
            fa.u[3] = lh ? I[b + 3] : J[b + 1];
            a[ks] = fa.s;
        }

        // rescale O by alpha of each O-row's query (fetch via bpermute)
        #pragma unroll
        for (int r = 0; r < 16; ++r) {
            int qr = (r & 3) + 8 * (r >> 2) + 4 * lh;
            float af = __shfl(alf, qr, 64);
            O0[r] *= af; O1[r] *= af;
        }

        // O += P @ V
        #pragma unroll
        for (int ks = 0; ks < 4; ++ks) {
            int kb = ks * 16 + lh * 8;
            s16x8 b0 = ldsfrag(sV + (size_t)lrow * PADK + kb);
            s16x8 b1 = ldsfrag(sV + (size_t)(32 + lrow) * PADK + kb);
            O0 = __builtin_amdgcn_mfma_f32_32x32x16_bf16(a[ks], b0, O0, 0, 0, 0);
            O1 = __builtin_amdgcn_mfma_f32_32x32x16_bf16(a[ks], b1, O1, 0, 0, 0);
        }
    }

    // store partials
    #pragma unroll
    for (int r = 0; r < 16; ++r) {
        int row = (r & 3) + 8 * (r >> 2) + 4 * lh;
        int grow = q0 + row;
        size_t ob = ((size_t)c * N_SEQ + grow) * 64;
        Opart[ob + lrow]      = O0[r];
        Opart[ob + 32 + lrow] = O1[r];
    }
    float lfull = lrun + __shfl_xor(lrun, 32, 64);
    if (lane < 32) {
        int grow = q0 + lrow;
        mpart[c * N_SEQ + grow] = mrow;
        lpart[c * N_SEQ + grow] = lfull;
    }
}

// ---------------- Kernel 4: combine split-K partials (float4) ----------------
__global__ __launch_bounds__(256) void combine(const float* __restrict__ Opart,
                                               const float* __restrict__ mpart,
                                               const float* __restrict__ lpart,
                                               float* __restrict__ out,
                                               int nsplit) {
    int idx = blockIdx.x * 256 + threadIdx.x;    // N_SEQ*16
    int row = idx >> 4, d4 = idx & 15;
    float M = -1e30f;
    for (int c = 0; c < nsplit; ++c) M = fmaxf(M, mpart[c * N_SEQ + row]);
    float4 num = make_float4(0.f, 0.f, 0.f, 0.f);
    float den = 0.f;
    for (int c = 0; c < nsplit; ++c) {
        float w = exp2f(mpart[c * N_SEQ + row] - M);
        den += w * lpart[c * N_SEQ + row];
        float4 o = ((const float4*)Opart)[((size_t)c * N_SEQ + row) * 16 + d4];
        num.x += w * o.x; num.y += w * o.y; num.z += w * o.z; num.w += w * o.w;
    }
    float inv = 1.0f / den;
    num.x *= inv; num.y *= inv; num.z *= inv; num.w *= inv;
    ((float4*)out)[idx] = num;
}

extern "C" void kernel_launch(void* const* d_in, const int* in_sizes, int n_in,
                              void* d_out, int out_size, void* d_ws, size_t ws_size,
                              hipStream_t stream) {
    const float* X  = (const float*)d_in[0];
    const float* WQ = (const float*)d_in[1];
    const float* WK = (const float*)d_in[2];
    const float* WV = (const float*)d_in[3];
    float* out = (float*)d_out;

    // workspace carve (Xhi/Xlo eliminated this round)
    const size_t szQK = (size_t)N_SEQ * 64 * 2;      // 1 MB each (bf16)
    const size_t szW  = (size_t)192 * E_DIM * 2;     // 288 KB each
    char* p = (char*)d_ws;
    unsigned short* Qhi = (unsigned short*)p; p += szQK;
    unsigned short* Qlo = (unsigned short*)p; p += szQK;
    unsigned short* Khi = (unsigned short*)p; p += szQK;
    unsigned short* Klo = (unsigned short*)p; p += szQK;
    unsigned short* Vt  = (unsigned short*)p; p += szQK;
    unsigned short* Wthi = (unsigned short*)p; p += szW;
    unsigned short* Wtlo = (unsigned short*)p; p += szW;
    size_t base = (size_t)(p - (char*)d_ws);
    size_t per  = (size_t)N_SEQ * 64 * 4 + 2 * (size_t)N_SEQ * 4;  // Opart + m + l per split
    int nsplit = 16;
    while (nsplit > 1 && base + (size_t)nsplit * per > ws_size) nsplit >>= 1;
    float* mpart = (float*)p; p += (size_t)nsplit * N_SEQ * 4;
    float* lpart = (float*)p; p += (size_t)nsplit * N_SEQ * 4;
    float* Opart = (float*)p;

    int chunk = N_SEQ / nsplit;

    prep_w<<<(192 * E_DIM + 255) / 256, 256, 0, stream>>>(WQ, WK, WV, Wthi, Wtlo);
    proj_qkv<<<512, 256, 0, stream>>>(X, Wthi, Wtlo, Qhi, Qlo, Khi, Klo, Vt);
    attn<<<dim3(nsplit, N_SEQ / 128), 256, 0, stream>>>(Qhi, Qlo, Khi, Klo, Vt,
                                                        Opart, mpart, lpart, chunk);
    combine<<<(N_SEQ * 16 + 255) / 256, 256, 0, stream>>>(Opart, mpart, lpart, out, nsplit);
}